// Round 2
// baseline (814.758 us; speedup 1.0000x reference)
//
#include <hip/hip_runtime.h>
#include <math.h>

#define BB 32
#define TT 512
#define EE 128
#define NHH 16
#define HDD 8
#define G3 384

__device__ __forceinline__ float sigmoidf_(float x) { return 1.0f / (1.0f + __expf(-x)); }

// K0: fold lookup/posres/attn_in into a 384x5 coefficient table:
// qkv[b,t,j] = u0[j]*g0 + u1[j]*g1 + cs[j]*sin(t) + cc[j]*cos(t) + cb[j]
__global__ void coef_kernel(const float* __restrict__ attn_in_w,
                            const float* __restrict__ attn_in_b,
                            const float* __restrict__ lookup_w,
                            const float* __restrict__ lookup_b,
                            const float* __restrict__ posres_w,
                            const float* __restrict__ posres_b,
                            float* __restrict__ coef) {
  int j = threadIdx.x;
  float u0 = 0.f, u1 = 0.f, cs = 0.f, cc = 0.f, cb = 0.f;
  const float* wrow = attn_in_w + j * EE;
  for (int e = 0; e < EE; ++e) {
    float w = wrow[e];
    float pw0 = posres_w[e * 2], pw1 = posres_w[e * 2 + 1];
    u0 += w * (lookup_w[e * 2] + pw0);
    u1 += w * (lookup_w[e * 2 + 1] + pw1);
    cs += w * pw0;
    cc += w * pw1;
    cb += w * (lookup_b[e] + posres_b[e]);
  }
  coef[0 * G3 + j] = u0;
  coef[1 * G3 + j] = u1;
  coef[2 * G3 + j] = cs;
  coef[3 * G3 + j] = cc;
  coef[4 * G3 + j] = cb + attn_in_b[j];
}

// K1: GRU. One block per (input s, batch b). 384 threads, thread j owns gate row j.
// w_hh row register-cached (128 VGPR), h broadcast from LDS as float4.
__global__ __launch_bounds__(384, 1) void gru_kernel(
    const float* __restrict__ in0, const float* __restrict__ in1,
    const float* __restrict__ in2, const int* __restrict__ len0,
    const int* __restrict__ len1, const int* __restrict__ len2,
    const float* __restrict__ w_ih, const float* __restrict__ w_hh,
    const float* __restrict__ b_ih, const float* __restrict__ b_hh,
    float* __restrict__ coor_embs) {
  int blk = blockIdx.x;
  int s = blk >> 5;
  int b = blk & 31;
  const float* inp = (s == 0) ? in0 : (s == 1) ? in1 : in2;
  const int* lenp = (s == 0) ? len0 : (s == 1) ? len1 : len2;
  int len = lenp[b];
  int j = threadIdx.x;

  __shared__ __align__(16) float hbuf[EE];
  __shared__ float gsum[256];
  __shared__ float xns[EE];
  __shared__ float hns[EE];
  __shared__ float xst[TT * 2];

  // stage coor channels (c=0,1) for this sequence
  for (int t = j; t < TT; t += 384) {
    float4 v = *(const float4*)(inp + ((size_t)b * TT + t) * 4);
    xst[t * 2] = v.x;
    xst[t * 2 + 1] = v.y;
  }
  if (j < EE) hbuf[j] = 0.0f;

  // preload this thread's w_hh row into registers
  float4 w[32];
  const float4* wr = (const float4*)(w_hh + (size_t)j * EE);
#pragma unroll
  for (int i = 0; i < 32; ++i) w[i] = wr[i];
  float wi0 = w_ih[j * 2], wi1 = w_ih[j * 2 + 1];
  float bi = b_ih[j], bh = b_hh[j];
  __syncthreads();

  const float4* h4 = (const float4*)hbuf;
  for (int t = 0; t < len; ++t) {
    float a0 = 0.f, a1 = 0.f, a2 = 0.f, a3 = 0.f;
#pragma unroll
    for (int i = 0; i < 32; ++i) {
      float4 hv = h4[i];
      a0 += w[i].x * hv.x;
      a1 += w[i].y * hv.y;
      a2 += w[i].z * hv.z;
      a3 += w[i].w * hv.w;
    }
    float hg = bh + ((a0 + a1) + (a2 + a3));
    float xg = bi + wi0 * xst[t * 2] + wi1 * xst[t * 2 + 1];
    if (j < 256) {
      gsum[j] = xg + hg;
    } else {
      xns[j - 256] = xg;
      hns[j - 256] = hg;
    }
    __syncthreads();
    if (j < EE) {
      float r = sigmoidf_(gsum[j]);
      float z = sigmoidf_(gsum[EE + j]);
      float n = tanhf(xns[j] + r * hns[j]);
      hbuf[j] = (1.0f - z) * n + z * hbuf[j];
    }
    __syncthreads();
  }
  if (j < EE) coor_embs[(size_t)blk * EE + j] = hbuf[j];
}

// K2: attention, one block per (s, b, head). Computes
// ohat[s,b,h,:] = sum_k w_k * v_k with w_k = (1/T) sum_q softmax_q(k).
__global__ __launch_bounds__(256) void attn_kernel(const float* __restrict__ in0,
                                                   const float* __restrict__ in1,
                                                   const float* __restrict__ in2,
                                                   const float* __restrict__ coef,
                                                   float* __restrict__ ohat) {
  int blk = blockIdx.x;  // s*512 + b*16 + h
  int s = blk >> 9;
  int bh = blk & 511;
  int b = bh >> 4;
  int h = bh & 15;
  const float* inp = (s == 0) ? in0 : (s == 1) ? in1 : in2;
  int tid = threadIdx.x;

  __shared__ __align__(16) float qL[TT * HDD];
  __shared__ __align__(16) float kL[TT * HDD];
  __shared__ __align__(16) float vL[TT * HDD];
  __shared__ float rZ[TT];
  __shared__ float red[4][HDD];

  // stage q/k/v for this head directly from grid channels + coef table
  for (int t = tid; t < TT; t += 256) {
    float ft = (float)t;
    float st = sinf(ft);
    float ct = cosf(ft);
    float4 g = *(const float4*)(inp + ((size_t)b * TT + t) * 4);
    float g0 = g.z, g1 = g.w;
#pragma unroll
    for (int d = 0; d < HDD; ++d) {
      int jq = h * HDD + d;
      int jk = EE + h * HDD + d;
      int jv = 2 * EE + h * HDD + d;
      qL[t * HDD + d] = coef[jq] * g0 + coef[G3 + jq] * g1 + coef[2 * G3 + jq] * st +
                        coef[3 * G3 + jq] * ct + coef[4 * G3 + jq];
      kL[t * HDD + d] = coef[jk] * g0 + coef[G3 + jk] * g1 + coef[2 * G3 + jk] * st +
                        coef[3 * G3 + jk] * ct + coef[4 * G3 + jk];
      vL[t * HDD + d] = coef[jv] * g0 + coef[G3 + jv] * g1 + coef[2 * G3 + jv] * st +
                        coef[3 * G3 + jv] * ct + coef[4 * G3 + jv];
    }
  }
  __syncthreads();

  const float scale = 0.35355339059327373f;  // 1/sqrt(8)

  // Phase A: per q-row denominators (scores tiny -> max-free softmax is safe)
  {
    float4 qa0 = *(const float4*)(qL + tid * HDD);
    float4 qb0 = *(const float4*)(qL + tid * HDD + 4);
    float4 qa1 = *(const float4*)(qL + (tid + 256) * HDD);
    float4 qb1 = *(const float4*)(qL + (tid + 256) * HDD + 4);
    float Z0 = 0.f, Z1 = 0.f;
    for (int k = 0; k < TT; ++k) {
      float4 ka = *(const float4*)(kL + k * HDD);
      float4 kb = *(const float4*)(kL + k * HDD + 4);
      float s0 = qa0.x * ka.x + qa0.y * ka.y + qa0.z * ka.z + qa0.w * ka.w +
                 qb0.x * kb.x + qb0.y * kb.y + qb0.z * kb.z + qb0.w * kb.w;
      float s1 = qa1.x * ka.x + qa1.y * ka.y + qa1.z * ka.z + qa1.w * ka.w +
                 qb1.x * kb.x + qb1.y * kb.y + qb1.z * kb.z + qb1.w * kb.w;
      Z0 += __expf(s0 * scale);
      Z1 += __expf(s1 * scale);
    }
    rZ[tid] = 1.0f / (Z0 * (float)TT);
    rZ[tid + 256] = 1.0f / (Z1 * (float)TT);
  }
  __syncthreads();

  // Phase B: thread owns k-rows, accumulates w_k = sum_q exp(s)/Z_q, then o = sum w_k v_k
  {
    float4 ka0 = *(const float4*)(kL + tid * HDD);
    float4 kb0 = *(const float4*)(kL + tid * HDD + 4);
    float4 ka1 = *(const float4*)(kL + (tid + 256) * HDD);
    float4 kb1 = *(const float4*)(kL + (tid + 256) * HDD + 4);
    float w0 = 0.f, w1 = 0.f;
    for (int q = 0; q < TT; ++q) {
      float4 qa = *(const float4*)(qL + q * HDD);
      float4 qb = *(const float4*)(qL + q * HDD + 4);
      float rz = rZ[q];
      float s0 = ka0.x * qa.x + ka0.y * qa.y + ka0.z * qa.z + ka0.w * qa.w +
                 kb0.x * qb.x + kb0.y * qb.y + kb0.z * qb.z + kb0.w * qb.w;
      float s1 = ka1.x * qa.x + ka1.y * qa.y + ka1.z * qa.z + ka1.w * qa.w +
                 kb1.x * qb.x + kb1.y * qb.y + kb1.z * qb.z + kb1.w * qb.w;
      w0 += __expf(s0 * scale) * rz;
      w1 += __expf(s1 * scale) * rz;
    }
    float4 va0 = *(const float4*)(vL + tid * HDD);
    float4 vb0 = *(const float4*)(vL + tid * HDD + 4);
    float4 va1 = *(const float4*)(vL + (tid + 256) * HDD);
    float4 vb1 = *(const float4*)(vL + (tid + 256) * HDD + 4);
    float od[HDD];
    od[0] = w0 * va0.x + w1 * va1.x;
    od[1] = w0 * va0.y + w1 * va1.y;
    od[2] = w0 * va0.z + w1 * va1.z;
    od[3] = w0 * va0.w + w1 * va1.w;
    od[4] = w0 * vb0.x + w1 * vb1.x;
    od[5] = w0 * vb0.y + w1 * vb1.y;
    od[6] = w0 * vb0.z + w1 * vb1.z;
    od[7] = w0 * vb0.w + w1 * vb1.w;
#pragma unroll
    for (int off = 32; off >= 1; off >>= 1) {
#pragma unroll
      for (int d = 0; d < HDD; ++d) od[d] += __shfl_xor(od[d], off, 64);
    }
    int wave = tid >> 6;
    int lane = tid & 63;
    if (lane == 0) {
#pragma unroll
      for (int d = 0; d < HDD; ++d) red[wave][d] = od[d];
    }
  }
  __syncthreads();
  if (tid < HDD) {
    float o = red[0][tid] + red[1][tid] + red[2][tid] + red[3][tid];
    ohat[(size_t)blk * HDD + tid] = o;
  }
}

// K3: grid_emb = ohat @ out_w.T + out_b ; out = gamma*coor + (1-gamma)*grid
__global__ __launch_bounds__(128) void finalize_kernel(
    const float* __restrict__ attn_out_w, const float* __restrict__ attn_out_b,
    const float* __restrict__ ohat, const float* __restrict__ coor_embs,
    const float* __restrict__ gamma_p, float* __restrict__ out) {
  int blk = blockIdx.x;  // s*32 + b
  int e = threadIdx.x;
  __shared__ float ov[EE];
  ov[e] = ohat[(size_t)blk * EE + e];
  __syncthreads();
  float acc = attn_out_b[e];
  const float* wrow = attn_out_w + (size_t)e * EE;
#pragma unroll 8
  for (int f = 0; f < EE; ++f) acc += wrow[f] * ov[f];
  float g = gamma_p[0];
  out[(size_t)blk * EE + e] = g * coor_embs[(size_t)blk * EE + e] + (1.0f - g) * acc;
}

// K4: pos/neg distances from the embeddings already in d_out
__global__ void dist_kernel(float* __restrict__ out) {
  int i = threadIdx.x;  // 64 threads
  int b = i & 31;
  int neg = i >> 5;
  const float* a = out + (size_t)b * EE;
  const float* x = out + (size_t)(1 + neg) * BB * EE + (size_t)b * EE;
  float sum = 0.f;
  for (int e = 0; e < EE; ++e) {
    float d = a[e] - x[e] + 1e-6f;
    sum += d * d;
  }
  out[3 * BB * EE + neg * BB + b] = expf(-sqrtf(sum));
}

extern "C" void kernel_launch(void* const* d_in, const int* in_sizes, int n_in,
                              void* d_out, int out_size, void* d_ws, size_t ws_size,
                              hipStream_t stream) {
  const float* a_in = (const float*)d_in[0];
  const float* p_in = (const float*)d_in[1];
  const float* ng_in = (const float*)d_in[2];
  const int* a_len = (const int*)d_in[3];
  const int* p_len = (const int*)d_in[4];
  const int* ng_len = (const int*)d_in[5];
  const float* w_ih = (const float*)d_in[6];
  const float* w_hh = (const float*)d_in[7];
  const float* b_ih = (const float*)d_in[8];
  const float* b_hh = (const float*)d_in[9];
  const float* lookup_w = (const float*)d_in[10];
  const float* lookup_b = (const float*)d_in[11];
  const float* posres_w = (const float*)d_in[12];
  const float* posres_b = (const float*)d_in[13];
  const float* attn_in_w = (const float*)d_in[14];
  const float* attn_in_b = (const float*)d_in[15];
  const float* attn_out_w = (const float*)d_in[16];
  const float* attn_out_b = (const float*)d_in[17];
  const float* gamma_p = (const float*)d_in[18];
  float* out = (float*)d_out;

  float* coef = (float*)d_ws;      // 5*384 = 1920 floats (pad to 2048)
  float* ohat = coef + 2048;       // 3*32*16*8 = 12288 floats
  float* cemb = ohat + 12288;      // 3*32*128  = 12288 floats

  hipLaunchKernelGGL(coef_kernel, dim3(1), dim3(384), 0, stream, attn_in_w,
                     attn_in_b, lookup_w, lookup_b, posres_w, posres_b, coef);
  hipLaunchKernelGGL(gru_kernel, dim3(96), dim3(384), 0, stream, a_in, p_in, ng_in,
                     a_len, p_len, ng_len, w_ih, w_hh, b_ih, b_hh, cemb);
  hipLaunchKernelGGL(attn_kernel, dim3(1536), dim3(256), 0, stream, a_in, p_in,
                     ng_in, coef, ohat);
  hipLaunchKernelGGL(finalize_kernel, dim3(96), dim3(128), 0, stream, attn_out_w,
                     attn_out_b, ohat, cemb, gamma_p, out);
  hipLaunchKernelGGL(dist_kernel, dim3(1), dim3(64), 0, stream, out);
}

// Round 3
// 734.884 us; speedup vs baseline: 1.1087x; 1.1087x over previous
//
#include <hip/hip_runtime.h>
#include <math.h>

#define BB 32
#define TT 512
#define EE 128
#define NHH 16
#define HDD 8
#define G3 384

__device__ __forceinline__ float sigmoidf_(float x) {
  return __builtin_amdgcn_rcpf(1.0f + __expf(-x));
}

// K0: fold lookup/posres/attn_in into a 384x5 coefficient table:
// qkv[b,t,j] = u0[j]*g0 + u1[j]*g1 + cs[j]*sin(t) + cc[j]*cos(t) + cb[j]
__global__ void coef_kernel(const float* __restrict__ attn_in_w,
                            const float* __restrict__ attn_in_b,
                            const float* __restrict__ lookup_w,
                            const float* __restrict__ lookup_b,
                            const float* __restrict__ posres_w,
                            const float* __restrict__ posres_b,
                            float* __restrict__ coef) {
  int j = threadIdx.x;
  float u0 = 0.f, u1 = 0.f, cs = 0.f, cc = 0.f, cb = 0.f;
  const float* wrow = attn_in_w + j * EE;
  for (int e = 0; e < EE; ++e) {
    float w = wrow[e];
    float pw0 = posres_w[e * 2], pw1 = posres_w[e * 2 + 1];
    u0 += w * (lookup_w[e * 2] + pw0);
    u1 += w * (lookup_w[e * 2 + 1] + pw1);
    cs += w * pw0;
    cc += w * pw1;
    cb += w * (lookup_b[e] + posres_b[e]);
  }
  coef[0 * G3 + j] = u0;
  coef[1 * G3 + j] = u1;
  coef[2 * G3 + j] = cs;
  coef[3 * G3 + j] = cc;
  coef[4 * G3 + j] = cb + attn_in_b[j];
}

// K1: GRU. One block per (input s, batch b). 512 threads = 128 groups of 4.
// Group g owns h-element e=g; the 4 lanes split the 128-dim dot over k-slices.
// Each thread computes partials for all 3 gate rows (e, e+128, e+256), the
// group reduces with 2 shfl_xor, then ALL lanes redundantly compute the
// nonlinearity (no cross-thread data needed). h double-buffered in LDS ->
// exactly ONE barrier per timestep; h-old stays in registers.
__global__ __launch_bounds__(512, 2) void gru_kernel(
    const float* __restrict__ in0, const float* __restrict__ in1,
    const float* __restrict__ in2, const int* __restrict__ len0,
    const int* __restrict__ len1, const int* __restrict__ len2,
    const float* __restrict__ w_ih, const float* __restrict__ w_hh,
    const float* __restrict__ b_ih, const float* __restrict__ b_hh,
    float* __restrict__ coor_embs) {
  int blk = blockIdx.x;
  int s = blk >> 5;
  int b = blk & 31;
  const float* inp = (s == 0) ? in0 : (s == 1) ? in1 : in2;
  const int* lenp = (s == 0) ? len0 : (s == 1) ? len1 : len2;
  int len = lenp[b];
  int tid = threadIdx.x;
  int e = tid >> 2;   // h element / gate index 0..127
  int kp = tid & 3;   // k-slice 0..3

  __shared__ __align__(16) float hb[2][EE];
  __shared__ __align__(16) float xst[TT * 2];

  // stage coor channels
  {
    int t = tid;
    float4 v = *(const float4*)(inp + ((size_t)b * TT + t) * 4);
    xst[t * 2] = v.x;
    xst[t * 2 + 1] = v.y;
  }
  if (tid < EE) hb[0][tid] = 0.0f;

  int rr = e, rz = e + 128, rn = e + 256;
  // interleaved k-slices: thread kp owns float4 blocks {4i+kp}, i=0..7.
  // LDS read addr = 64*i + 16*kp bytes -> 4 distinct broadcast addrs per
  // wave-instruction covering 16 banks: conflict-free.
  float4 wr_[8], wz_[8], wn_[8];
  {
    const float4* pr = (const float4*)(w_hh + (size_t)rr * EE);
    const float4* pz = (const float4*)(w_hh + (size_t)rz * EE);
    const float4* pn = (const float4*)(w_hh + (size_t)rn * EE);
#pragma unroll
    for (int i = 0; i < 8; ++i) {
      wr_[i] = pr[4 * i + kp];
      wz_[i] = pz[4 * i + kp];
      wn_[i] = pn[4 * i + kp];
    }
  }
  float br = b_ih[rr] + b_hh[rr];
  float bz = b_ih[rz] + b_hh[rz];
  float bn = b_ih[rn];
  float bhn = b_hh[rn];
  float wir0 = w_ih[rr * 2], wir1 = w_ih[rr * 2 + 1];
  float wiz0 = w_ih[rz * 2], wiz1 = w_ih[rz * 2 + 1];
  float win0 = w_ih[rn * 2], win1 = w_ih[rn * 2 + 1];

  float hold = 0.0f;
  __syncthreads();

#pragma unroll 1
  for (int t = 0; t < len; ++t) {
    const float4* h4 = (const float4*)(hb[t & 1]);
    float hr0 = 0.f, hr1 = 0.f, hz0 = 0.f, hz1 = 0.f, hn0 = 0.f, hn1 = 0.f;
#pragma unroll
    for (int i = 0; i < 8; i += 2) {
      float4 ha = h4[4 * i + kp];
      float4 hbv = h4[4 * (i + 1) + kp];
      hr0 += wr_[i].x * ha.x + wr_[i].y * ha.y + wr_[i].z * ha.z + wr_[i].w * ha.w;
      hz0 += wz_[i].x * ha.x + wz_[i].y * ha.y + wz_[i].z * ha.z + wz_[i].w * ha.w;
      hn0 += wn_[i].x * ha.x + wn_[i].y * ha.y + wn_[i].z * ha.z + wn_[i].w * ha.w;
      hr1 += wr_[i + 1].x * hbv.x + wr_[i + 1].y * hbv.y + wr_[i + 1].z * hbv.z +
             wr_[i + 1].w * hbv.w;
      hz1 += wz_[i + 1].x * hbv.x + wz_[i + 1].y * hbv.y + wz_[i + 1].z * hbv.z +
             wz_[i + 1].w * hbv.w;
      hn1 += wn_[i + 1].x * hbv.x + wn_[i + 1].y * hbv.y + wn_[i + 1].z * hbv.z +
             wn_[i + 1].w * hbv.w;
    }
    float hr = hr0 + hr1, hz = hz0 + hz1, hn = hn0 + hn1;
    // 4-lane group reduce (lanes 4e..4e+3 are in the same wave)
    hr += __shfl_xor(hr, 1);
    hz += __shfl_xor(hz, 1);
    hn += __shfl_xor(hn, 1);
    hr += __shfl_xor(hr, 2);
    hz += __shfl_xor(hz, 2);
    hn += __shfl_xor(hn, 2);

    float x0 = xst[t * 2], x1 = xst[t * 2 + 1];
    float r = sigmoidf_(br + wir0 * x0 + wir1 * x1 + hr);
    float z = sigmoidf_(bz + wiz0 * x0 + wiz1 * x1 + hz);
    float targ = bn + win0 * x0 + win1 * x1 + r * (bhn + hn);
    float ex = __expf(2.0f * targ);
    float n = 1.0f - 2.0f * __builtin_amdgcn_rcpf(ex + 1.0f);  // tanh
    hold = n + z * (hold - n);
    if (kp == 0) hb[(t & 1) ^ 1][e] = hold;
    __syncthreads();
  }
  if (kp == 0) coor_embs[(size_t)blk * EE + e] = hold;
}

// K2: attention, one block per (s, b, head). Computes
// ohat[s,b,h,:] = sum_k w_k * v_k with w_k = (1/T) sum_q softmax_q(k).
__global__ __launch_bounds__(256) void attn_kernel(const float* __restrict__ in0,
                                                   const float* __restrict__ in1,
                                                   const float* __restrict__ in2,
                                                   const float* __restrict__ coef,
                                                   float* __restrict__ ohat) {
  int blk = blockIdx.x;  // s*512 + b*16 + h
  int s = blk >> 9;
  int bh = blk & 511;
  int b = bh >> 4;
  int h = bh & 15;
  const float* inp = (s == 0) ? in0 : (s == 1) ? in1 : in2;
  int tid = threadIdx.x;

  __shared__ __align__(16) float qL[TT * HDD];
  __shared__ __align__(16) float kL[TT * HDD];
  __shared__ __align__(16) float vL[TT * HDD];
  __shared__ float rZ[TT];
  __shared__ float red[4][HDD];

  // stage q/k/v for this head directly from grid channels + coef table
  for (int t = tid; t < TT; t += 256) {
    float ft = (float)t;
    float st = sinf(ft);
    float ct = cosf(ft);
    float4 g = *(const float4*)(inp + ((size_t)b * TT + t) * 4);
    float g0 = g.z, g1 = g.w;
#pragma unroll
    for (int d = 0; d < HDD; ++d) {
      int jq = h * HDD + d;
      int jk = EE + h * HDD + d;
      int jv = 2 * EE + h * HDD + d;
      qL[t * HDD + d] = coef[jq] * g0 + coef[G3 + jq] * g1 + coef[2 * G3 + jq] * st +
                        coef[3 * G3 + jq] * ct + coef[4 * G3 + jq];
      kL[t * HDD + d] = coef[jk] * g0 + coef[G3 + jk] * g1 + coef[2 * G3 + jk] * st +
                        coef[3 * G3 + jk] * ct + coef[4 * G3 + jk];
      vL[t * HDD + d] = coef[jv] * g0 + coef[G3 + jv] * g1 + coef[2 * G3 + jv] * st +
                        coef[3 * G3 + jv] * ct + coef[4 * G3 + jv];
    }
  }
  __syncthreads();

  const float scale = 0.35355339059327373f;  // 1/sqrt(8)

  // Phase A: per q-row denominators (scores tiny -> max-free softmax is safe)
  {
    float4 qa0 = *(const float4*)(qL + tid * HDD);
    float4 qb0 = *(const float4*)(qL + tid * HDD + 4);
    float4 qa1 = *(const float4*)(qL + (tid + 256) * HDD);
    float4 qb1 = *(const float4*)(qL + (tid + 256) * HDD + 4);
    float Z0 = 0.f, Z1 = 0.f;
    for (int k = 0; k < TT; ++k) {
      float4 ka = *(const float4*)(kL + k * HDD);
      float4 kb = *(const float4*)(kL + k * HDD + 4);
      float s0 = qa0.x * ka.x + qa0.y * ka.y + qa0.z * ka.z + qa0.w * ka.w +
                 qb0.x * kb.x + qb0.y * kb.y + qb0.z * kb.z + qb0.w * kb.w;
      float s1 = qa1.x * ka.x + qa1.y * ka.y + qa1.z * ka.z + qa1.w * ka.w +
                 qb1.x * kb.x + qb1.y * kb.y + qb1.z * kb.z + qb1.w * kb.w;
      Z0 += __expf(s0 * scale);
      Z1 += __expf(s1 * scale);
    }
    rZ[tid] = 1.0f / (Z0 * (float)TT);
    rZ[tid + 256] = 1.0f / (Z1 * (float)TT);
  }
  __syncthreads();

  // Phase B: thread owns k-rows, accumulates w_k = sum_q exp(s)/Z_q, then o = sum w_k v_k
  {
    float4 ka0 = *(const float4*)(kL + tid * HDD);
    float4 kb0 = *(const float4*)(kL + tid * HDD + 4);
    float4 ka1 = *(const float4*)(kL + (tid + 256) * HDD);
    float4 kb1 = *(const float4*)(kL + (tid + 256) * HDD + 4);
    float w0 = 0.f, w1 = 0.f;
    for (int q = 0; q < TT; ++q) {
      float4 qa = *(const float4*)(qL + q * HDD);
      float4 qb = *(const float4*)(qL + q * HDD + 4);
      float rz = rZ[q];
      float s0 = ka0.x * qa.x + ka0.y * qa.y + ka0.z * qa.z + ka0.w * qa.w +
                 kb0.x * qb.x + kb0.y * qb.y + kb0.z * qb.z + kb0.w * qb.w;
      float s1 = ka1.x * qa.x + ka1.y * qa.y + ka1.z * qa.z + ka1.w * qa.w +
                 kb1.x * qb.x + kb1.y * qb.y + kb1.z * qb.z + kb1.w * qb.w;
      w0 += __expf(s0 * scale) * rz;
      w1 += __expf(s1 * scale) * rz;
    }
    float4 va0 = *(const float4*)(vL + tid * HDD);
    float4 vb0 = *(const float4*)(vL + tid * HDD + 4);
    float4 va1 = *(const float4*)(vL + (tid + 256) * HDD);
    float4 vb1 = *(const float4*)(vL + (tid + 256) * HDD + 4);
    float od[HDD];
    od[0] = w0 * va0.x + w1 * va1.x;
    od[1] = w0 * va0.y + w1 * va1.y;
    od[2] = w0 * va0.z + w1 * va1.z;
    od[3] = w0 * va0.w + w1 * va1.w;
    od[4] = w0 * vb0.x + w1 * vb1.x;
    od[5] = w0 * vb0.y + w1 * vb1.y;
    od[6] = w0 * vb0.z + w1 * vb1.z;
    od[7] = w0 * vb0.w + w1 * vb1.w;
#pragma unroll
    for (int off = 32; off >= 1; off >>= 1) {
#pragma unroll
      for (int d = 0; d < HDD; ++d) od[d] += __shfl_xor(od[d], off, 64);
    }
    int wave = tid >> 6;
    int lane = tid & 63;
    if (lane == 0) {
#pragma unroll
      for (int d = 0; d < HDD; ++d) red[wave][d] = od[d];
    }
  }
  __syncthreads();
  if (tid < HDD) {
    float o = red[0][tid] + red[1][tid] + red[2][tid] + red[3][tid];
    ohat[(size_t)blk * HDD + tid] = o;
  }
}

// K3: grid_emb = ohat @ out_w.T + out_b ; out = gamma*coor + (1-gamma)*grid
__global__ __launch_bounds__(128) void finalize_kernel(
    const float* __restrict__ attn_out_w, const float* __restrict__ attn_out_b,
    const float* __restrict__ ohat, const float* __restrict__ coor_embs,
    const float* __restrict__ gamma_p, float* __restrict__ out) {
  int blk = blockIdx.x;  // s*32 + b
  int e = threadIdx.x;
  __shared__ float ov[EE];
  ov[e] = ohat[(size_t)blk * EE + e];
  __syncthreads();
  float acc = attn_out_b[e];
  const float* wrow = attn_out_w + (size_t)e * EE;
#pragma unroll 8
  for (int f = 0; f < EE; ++f) acc += wrow[f] * ov[f];
  float g = gamma_p[0];
  out[(size_t)blk * EE + e] = g * coor_embs[(size_t)blk * EE + e] + (1.0f - g) * acc;
}

// K4: pos/neg distances from the embeddings already in d_out
__global__ void dist_kernel(float* __restrict__ out) {
  int i = threadIdx.x;  // 64 threads
  int b = i & 31;
  int neg = i >> 5;
  const float* a = out + (size_t)b * EE;
  const float* x = out + (size_t)(1 + neg) * BB * EE + (size_t)b * EE;
  float sum = 0.f;
  for (int e = 0; e < EE; ++e) {
    float d = a[e] - x[e] + 1e-6f;
    sum += d * d;
  }
  out[3 * BB * EE + neg * BB + b] = expf(-sqrtf(sum));
}

extern "C" void kernel_launch(void* const* d_in, const int* in_sizes, int n_in,
                              void* d_out, int out_size, void* d_ws, size_t ws_size,
                              hipStream_t stream) {
  const float* a_in = (const float*)d_in[0];
  const float* p_in = (const float*)d_in[1];
  const float* ng_in = (const float*)d_in[2];
  const int* a_len = (const int*)d_in[3];
  const int* p_len = (const int*)d_in[4];
  const int* ng_len = (const int*)d_in[5];
  const float* w_ih = (const float*)d_in[6];
  const float* w_hh = (const float*)d_in[7];
  const float* b_ih = (const float*)d_in[8];
  const float* b_hh = (const float*)d_in[9];
  const float* lookup_w = (const float*)d_in[10];
  const float* lookup_b = (const float*)d_in[11];
  const float* posres_w = (const float*)d_in[12];
  const float* posres_b = (const float*)d_in[13];
  const float* attn_in_w = (const float*)d_in[14];
  const float* attn_in_b = (const float*)d_in[15];
  const float* attn_out_w = (const float*)d_in[16];
  const float* attn_out_b = (const float*)d_in[17];
  const float* gamma_p = (const float*)d_in[18];
  float* out = (float*)d_out;

  float* coef = (float*)d_ws;      // 5*384 = 1920 floats (pad to 2048)
  float* ohat = coef + 2048;       // 3*32*16*8 = 12288 floats
  float* cemb = ohat + 12288;      // 3*32*128  = 12288 floats

  hipLaunchKernelGGL(coef_kernel, dim3(1), dim3(384), 0, stream, attn_in_w,
                     attn_in_b, lookup_w, lookup_b, posres_w, posres_b, coef);
  hipLaunchKernelGGL(attn_kernel, dim3(1536), dim3(256), 0, stream, a_in, p_in,
                     ng_in, coef, ohat);
  hipLaunchKernelGGL(gru_kernel, dim3(96), dim3(512), 0, stream, a_in, p_in, ng_in,
                     a_len, p_len, ng_len, w_ih, w_hh, b_ih, b_hh, cemb);
  hipLaunchKernelGGL(finalize_kernel, dim3(96), dim3(128), 0, stream, attn_out_w,
                     attn_out_b, ohat, cemb, gamma_p, out);
  hipLaunchKernelGGL(dist_kernel, dim3(1), dim3(64), 0, stream, out);
}

// Round 5
// 580.198 us; speedup vs baseline: 1.4043x; 1.2666x over previous
//
#include <hip/hip_runtime.h>
#include <math.h>

#define BB 32
#define TT 512
#define EE 128
#define NHH 16
#define HDD 8
#define G3 384

__device__ __forceinline__ float sigmoidf_(float x) {
  return __builtin_amdgcn_rcpf(1.0f + __expf(-x));
}

__device__ __forceinline__ float exp2_(float x) {
#if __has_builtin(__builtin_amdgcn_exp2f)
  return __builtin_amdgcn_exp2f(x);
#else
  return exp2f(x);
#endif
}

#define DOT4(p, q) fmaf((p).x, (q).x, fmaf((p).y, (q).y, fmaf((p).z, (q).z, (p).w * (q).w)))
#define DOT8(a, b, c, d)                                                      \
  fmaf((a).x, (c).x,                                                          \
       fmaf((a).y, (c).y,                                                     \
            fmaf((a).z, (c).z,                                                \
                 fmaf((a).w, (c).w,                                           \
                      fmaf((b).x, (d).x,                                      \
                           fmaf((b).y, (d).y,                                 \
                                fmaf((b).z, (d).z, (b).w * (d).w)))))))

// K0: fold lookup/posres/attn_in into a 384x5 coefficient table:
// qkv[b,t,j] = u0[j]*g0 + u1[j]*g1 + cs[j]*sin(t) + cc[j]*cos(t) + cb[j]
__global__ void coef_kernel(const float* __restrict__ attn_in_w,
                            const float* __restrict__ attn_in_b,
                            const float* __restrict__ lookup_w,
                            const float* __restrict__ lookup_b,
                            const float* __restrict__ posres_w,
                            const float* __restrict__ posres_b,
                            float* __restrict__ coef) {
  int j = threadIdx.x;
  float u0 = 0.f, u1 = 0.f, cs = 0.f, cc = 0.f, cb = 0.f;
  const float* wrow = attn_in_w + j * EE;
  for (int e = 0; e < EE; ++e) {
    float w = wrow[e];
    float pw0 = posres_w[e * 2], pw1 = posres_w[e * 2 + 1];
    u0 += w * (lookup_w[e * 2] + pw0);
    u1 += w * (lookup_w[e * 2 + 1] + pw1);
    cs += w * pw0;
    cc += w * pw1;
    cb += w * (lookup_b[e] + posres_b[e]);
  }
  coef[0 * G3 + j] = u0;
  coef[1 * G3 + j] = u1;
  coef[2 * G3 + j] = cs;
  coef[3 * G3 + j] = cc;
  coef[4 * G3 + j] = cb + attn_in_b[j];
}

// K1: GRU. One block per (input s, batch b). 512 threads = 128 groups of 4.
// Weights held in 24 NAMED float4 registers (no arrays -> no remat/spill).
__global__ __launch_bounds__(512, 2) void gru_kernel(
    const float* __restrict__ in0, const float* __restrict__ in1,
    const float* __restrict__ in2, const int* __restrict__ len0,
    const int* __restrict__ len1, const int* __restrict__ len2,
    const float* __restrict__ w_ih, const float* __restrict__ w_hh,
    const float* __restrict__ b_ih, const float* __restrict__ b_hh,
    float* __restrict__ coor_embs) {
  int blk = blockIdx.x;
  int s = blk >> 5;
  int b = blk & 31;
  const float* inp = (s == 0) ? in0 : (s == 1) ? in1 : in2;
  const int* lenp = (s == 0) ? len0 : (s == 1) ? len1 : len2;
  int len = lenp[b];
  int tid = threadIdx.x;
  int e = tid >> 2;   // h element / gate index 0..127
  int kp = tid & 3;   // k-slice 0..3

  __shared__ __align__(16) float hb[2][EE];
  __shared__ __align__(16) float xst[TT * 2];

  {
    int t = tid;
    float4 v = *(const float4*)(inp + ((size_t)b * TT + t) * 4);
    xst[t * 2] = v.x;
    xst[t * 2 + 1] = v.y;
  }
  if (tid < EE) hb[0][tid] = 0.0f;

  int rr = e, rz = e + 128, rn = e + 256;
  const float* prr = w_hh + (size_t)rr * EE + 4 * kp;
  const float* prz = w_hh + (size_t)rz * EE + 4 * kp;
  const float* prn = w_hh + (size_t)rn * EE + 4 * kp;
#define LD4(p) (*(const float4*)(p))
  float4 wr0 = LD4(prr + 0),  wr1 = LD4(prr + 16), wr2 = LD4(prr + 32),
         wr3 = LD4(prr + 48), wr4 = LD4(prr + 64), wr5 = LD4(prr + 80),
         wr6 = LD4(prr + 96), wr7 = LD4(prr + 112);
  float4 wz0 = LD4(prz + 0),  wz1 = LD4(prz + 16), wz2 = LD4(prz + 32),
         wz3 = LD4(prz + 48), wz4 = LD4(prz + 64), wz5 = LD4(prz + 80),
         wz6 = LD4(prz + 96), wz7 = LD4(prz + 112);
  float4 wn0 = LD4(prn + 0),  wn1 = LD4(prn + 16), wn2 = LD4(prn + 32),
         wn3 = LD4(prn + 48), wn4 = LD4(prn + 64), wn5 = LD4(prn + 80),
         wn6 = LD4(prn + 96), wn7 = LD4(prn + 112);

  float br = b_ih[rr] + b_hh[rr];
  float bz = b_ih[rz] + b_hh[rz];
  float bn = b_ih[rn];
  float bhn = b_hh[rn];
  float wir0 = w_ih[rr * 2], wir1 = w_ih[rr * 2 + 1];
  float wiz0 = w_ih[rz * 2], wiz1 = w_ih[rz * 2 + 1];
  float win0 = w_ih[rn * 2], win1 = w_ih[rn * 2 + 1];

  float hold = 0.0f;
  __syncthreads();

#pragma unroll 1
  for (int t = 0; t < len; ++t) {
    const float* hrow = hb[t & 1] + 4 * kp;
    float4 h0 = LD4(hrow + 0),  h1 = LD4(hrow + 16), h2 = LD4(hrow + 32),
           h3 = LD4(hrow + 48), h4v = LD4(hrow + 64), h5 = LD4(hrow + 80),
           h6 = LD4(hrow + 96), h7 = LD4(hrow + 112);
    float x0 = xst[t * 2], x1 = xst[t * 2 + 1];

    float hra = DOT4(wr0, h0) + DOT4(wr1, h1) + DOT4(wr2, h2) + DOT4(wr3, h3);
    float hrb = DOT4(wr4, h4v) + DOT4(wr5, h5) + DOT4(wr6, h6) + DOT4(wr7, h7);
    float hza = DOT4(wz0, h0) + DOT4(wz1, h1) + DOT4(wz2, h2) + DOT4(wz3, h3);
    float hzb = DOT4(wz4, h4v) + DOT4(wz5, h5) + DOT4(wz6, h6) + DOT4(wz7, h7);
    float hna = DOT4(wn0, h0) + DOT4(wn1, h1) + DOT4(wn2, h2) + DOT4(wn3, h3);
    float hnb = DOT4(wn4, h4v) + DOT4(wn5, h5) + DOT4(wn6, h6) + DOT4(wn7, h7);
    float hr = hra + hrb, hz = hza + hzb, hn = hna + hnb;

    hr += __shfl_xor(hr, 1);
    hz += __shfl_xor(hz, 1);
    hn += __shfl_xor(hn, 1);
    hr += __shfl_xor(hr, 2);
    hz += __shfl_xor(hz, 2);
    hn += __shfl_xor(hn, 2);

    float r = sigmoidf_(br + wir0 * x0 + wir1 * x1 + hr);
    float z = sigmoidf_(bz + wiz0 * x0 + wiz1 * x1 + hz);
    float targ = bn + win0 * x0 + win1 * x1 + r * (bhn + hn);
    float ex = __expf(2.0f * targ);
    float n = 1.0f - 2.0f * __builtin_amdgcn_rcpf(ex + 1.0f);  // tanh
    hold = n + z * (hold - n);
    if (kp == 0) hb[(t & 1) ^ 1][e] = hold;
    __syncthreads();
  }
  if (kp == 0) coor_embs[(size_t)blk * EE + e] = hold;
}

// K2: attention, one block per (s, b, head).
// qL pre-scaled by (1/sqrt(HD))*log2(e) so score feeds v_exp_f32 directly.
__global__ __launch_bounds__(256) void attn_kernel(const float* __restrict__ in0,
                                                   const float* __restrict__ in1,
                                                   const float* __restrict__ in2,
                                                   const float* __restrict__ coef,
                                                   float* __restrict__ ohat) {
  int blk = blockIdx.x;  // s*512 + b*16 + h
  int s = blk >> 9;
  int bh = blk & 511;
  int b = bh >> 4;
  int h = bh & 15;
  const float* inp = (s == 0) ? in0 : (s == 1) ? in1 : in2;
  int tid = threadIdx.x;

  __shared__ __align__(16) float qL[TT * HDD];
  __shared__ __align__(16) float kL[TT * HDD];
  __shared__ __align__(16) float vL[TT * HDD];
  __shared__ float rZ[TT];
  __shared__ float red[4][HDD];

  const float SCL = 0.35355339059327373f * 1.4426950408889634f;

  for (int t = tid; t < TT; t += 256) {
    float ft = (float)t;
    float st = sinf(ft);
    float ct = cosf(ft);
    float4 g = *(const float4*)(inp + ((size_t)b * TT + t) * 4);
    float g0 = g.z, g1 = g.w;
#pragma unroll
    for (int d = 0; d < HDD; ++d) {
      int jq = h * HDD + d;
      int jk = EE + h * HDD + d;
      int jv = 2 * EE + h * HDD + d;
      float qv = coef[jq] * g0 + coef[G3 + jq] * g1 + coef[2 * G3 + jq] * st +
                 coef[3 * G3 + jq] * ct + coef[4 * G3 + jq];
      qL[t * HDD + d] = qv * SCL;
      kL[t * HDD + d] = coef[jk] * g0 + coef[G3 + jk] * g1 + coef[2 * G3 + jk] * st +
                        coef[3 * G3 + jk] * ct + coef[4 * G3 + jk];
      vL[t * HDD + d] = coef[jv] * g0 + coef[G3 + jv] * g1 + coef[2 * G3 + jv] * st +
                        coef[3 * G3 + jv] * ct + coef[4 * G3 + jv];
    }
  }
  __syncthreads();

  // Phase A: per q-row denominators (scores tiny -> max-free softmax is safe)
  {
    float4 qa0 = *(const float4*)(qL + tid * HDD);
    float4 qb0 = *(const float4*)(qL + tid * HDD + 4);
    float4 qa1 = *(const float4*)(qL + (tid + 256) * HDD);
    float4 qb1 = *(const float4*)(qL + (tid + 256) * HDD + 4);
    float Z0a = 0.f, Z0b = 0.f, Z1a = 0.f, Z1b = 0.f;
#pragma unroll 1
    for (int k = 0; k < TT; k += 2) {
      float4 ka = *(const float4*)(kL + k * HDD);
      float4 kb = *(const float4*)(kL + k * HDD + 4);
      float4 kc = *(const float4*)(kL + (k + 1) * HDD);
      float4 kd = *(const float4*)(kL + (k + 1) * HDD + 4);
      Z0a += exp2_(DOT8(qa0, qb0, ka, kb));
      Z0b += exp2_(DOT8(qa0, qb0, kc, kd));
      Z1a += exp2_(DOT8(qa1, qb1, ka, kb));
      Z1b += exp2_(DOT8(qa1, qb1, kc, kd));
    }
    rZ[tid] = 1.0f / ((Z0a + Z0b) * (float)TT);
    rZ[tid + 256] = 1.0f / ((Z1a + Z1b) * (float)TT);
  }
  __syncthreads();

  // Phase B: thread owns k-rows, accumulates w_k = sum_q exp(s)/Z_q
  {
    float4 ka0 = *(const float4*)(kL + tid * HDD);
    float4 kb0 = *(const float4*)(kL + tid * HDD + 4);
    float4 ka1 = *(const float4*)(kL + (tid + 256) * HDD);
    float4 kb1 = *(const float4*)(kL + (tid + 256) * HDD + 4);
    float w0a = 0.f, w0b = 0.f, w1a = 0.f, w1b = 0.f;
#pragma unroll 1
    for (int q = 0; q < TT; q += 2) {
      float4 qa = *(const float4*)(qL + q * HDD);
      float4 qb = *(const float4*)(qL + q * HDD + 4);
      float4 qc = *(const float4*)(qL + (q + 1) * HDD);
      float4 qd = *(const float4*)(qL + (q + 1) * HDD + 4);
      float rza = rZ[q];
      float rzb = rZ[q + 1];
      w0a = fmaf(exp2_(DOT8(ka0, kb0, qa, qb)), rza, w0a);
      w0b = fmaf(exp2_(DOT8(ka0, kb0, qc, qd)), rzb, w0b);
      w1a = fmaf(exp2_(DOT8(ka1, kb1, qa, qb)), rza, w1a);
      w1b = fmaf(exp2_(DOT8(ka1, kb1, qc, qd)), rzb, w1b);
    }
    float w0 = w0a + w0b, w1 = w1a + w1b;
    float4 va0 = *(const float4*)(vL + tid * HDD);
    float4 vb0 = *(const float4*)(vL + tid * HDD + 4);
    float4 va1 = *(const float4*)(vL + (tid + 256) * HDD);
    float4 vb1 = *(const float4*)(vL + (tid + 256) * HDD + 4);
    float od[HDD];
    od[0] = w0 * va0.x + w1 * va1.x;
    od[1] = w0 * va0.y + w1 * va1.y;
    od[2] = w0 * va0.z + w1 * va1.z;
    od[3] = w0 * va0.w + w1 * va1.w;
    od[4] = w0 * vb0.x + w1 * vb1.x;
    od[5] = w0 * vb0.y + w1 * vb1.y;
    od[6] = w0 * vb0.z + w1 * vb1.z;
    od[7] = w0 * vb0.w + w1 * vb1.w;
#pragma unroll
    for (int off = 32; off >= 1; off >>= 1) {
#pragma unroll
      for (int d = 0; d < HDD; ++d) od[d] += __shfl_xor(od[d], off, 64);
    }
    int wave = tid >> 6;
    int lane = tid & 63;
    if (lane == 0) {
#pragma unroll
      for (int d = 0; d < HDD; ++d) red[wave][d] = od[d];
    }
  }
  __syncthreads();
  if (tid < HDD) {
    float o = red[0][tid] + red[1][tid] + red[2][tid] + red[3][tid];
    ohat[(size_t)blk * HDD + tid] = o;
  }
}

// K3: grid_emb = ohat @ out_w.T + out_b ; out = gamma*coor + (1-gamma)*grid
__global__ __launch_bounds__(128) void finalize_kernel(
    const float* __restrict__ attn_out_w, const float* __restrict__ attn_out_b,
    const float* __restrict__ ohat, const float* __restrict__ coor_embs,
    const float* __restrict__ gamma_p, float* __restrict__ out) {
  int blk = blockIdx.x;  // s*32 + b
  int e = threadIdx.x;
  __shared__ float ov[EE];
  ov[e] = ohat[(size_t)blk * EE + e];
  __syncthreads();
  float acc = attn_out_b[e];
  const float* wrow = attn_out_w + (size_t)e * EE;
#pragma unroll 8
  for (int f = 0; f < EE; ++f) acc += wrow[f] * ov[f];
  float g = gamma_p[0];
  out[(size_t)blk * EE + e] = g * coor_embs[(size_t)blk * EE + e] + (1.0f - g) * acc;
}

// K4: pos/neg distances from the embeddings already in d_out
__global__ void dist_kernel(float* __restrict__ out) {
  int i = threadIdx.x;  // 64 threads
  int b = i & 31;
  int neg = i >> 5;
  const float* a = out + (size_t)b * EE;
  const float* x = out + (size_t)(1 + neg) * BB * EE + (size_t)b * EE;
  float sum = 0.f;
  for (int e = 0; e < EE; ++e) {
    float d = a[e] - x[e] + 1e-6f;
    sum += d * d;
  }
  out[3 * BB * EE + neg * BB + b] = expf(-sqrtf(sum));
}

extern "C" void kernel_launch(void* const* d_in, const int* in_sizes, int n_in,
                              void* d_out, int out_size, void* d_ws, size_t ws_size,
                              hipStream_t stream) {
  const float* a_in = (const float*)d_in[0];
  const float* p_in = (const float*)d_in[1];
  const float* ng_in = (const float*)d_in[2];
  const int* a_len = (const int*)d_in[3];
  const int* p_len = (const int*)d_in[4];
  const int* ng_len = (const int*)d_in[5];
  const float* w_ih = (const float*)d_in[6];
  const float* w_hh = (const float*)d_in[7];
  const float* b_ih = (const float*)d_in[8];
  const float* b_hh = (const float*)d_in[9];
  const float* lookup_w = (const float*)d_in[10];
  const float* lookup_b = (const float*)d_in[11];
  const float* posres_w = (const float*)d_in[12];
  const float* posres_b = (const float*)d_in[13];
  const float* attn_in_w = (const float*)d_in[14];
  const float* attn_in_b = (const float*)d_in[15];
  const float* attn_out_w = (const float*)d_in[16];
  const float* attn_out_b = (const float*)d_in[17];
  const float* gamma_p = (const float*)d_in[18];
  float* out = (float*)d_out;

  float* coef = (float*)d_ws;      // 5*384 = 1920 floats (pad to 2048)
  float* ohat = coef + 2048;       // 3*32*16*8 = 12288 floats
  float* cemb = ohat + 12288;      // 3*32*128  = 12288 floats

  hipLaunchKernelGGL(coef_kernel, dim3(1), dim3(384), 0, stream, attn_in_w,
                     attn_in_b, lookup_w, lookup_b, posres_w, posres_b, coef);
  hipLaunchKernelGGL(attn_kernel, dim3(1536), dim3(256), 0, stream, a_in, p_in,
                     ng_in, coef, ohat);
  hipLaunchKernelGGL(gru_kernel, dim3(96), dim3(512), 0, stream, a_in, p_in, ng_in,
                     a_len, p_len, ng_len, w_ih, w_hh, b_ih, b_hh, cemb);
  hipLaunchKernelGGL(finalize_kernel, dim3(96), dim3(128), 0, stream, attn_out_w,
                     attn_out_b, ohat, cemb, gamma_p, out);
  hipLaunchKernelGGL(dist_kernel, dim3(1), dim3(64), 0, stream, out);
}

// Round 6
// 504.166 us; speedup vs baseline: 1.6160x; 1.1508x over previous
//
#include <hip/hip_runtime.h>
#include <math.h>

#define BB 32
#define TT 512
#define EE 128
#define NHH 16
#define HDD 8
#define G3 384

__device__ __forceinline__ float sigmoidf_(float x) {
  return __builtin_amdgcn_rcpf(1.0f + __expf(-x));
}

__device__ __forceinline__ float exp2_(float x) {
#if __has_builtin(__builtin_amdgcn_exp2f)
  return __builtin_amdgcn_exp2f(x);
#else
  return exp2f(x);
#endif
}

#define DOT4(p, q) fmaf((p).x, (q).x, fmaf((p).y, (q).y, fmaf((p).z, (q).z, (p).w * (q).w)))
// 5-term: dot(p,m) + n as a single fma chain
#define SC5(p, m, n) \
  fmaf((p).x, (m).x, fmaf((p).y, (m).y, fmaf((p).z, (m).z, fmaf((p).w, (m).w, (n)))))

// K0: fold lookup/posres/attn_in into coef[5][384] and per-head 5x5 M (scaled).
// qkv[b,t,j] = sum_i coef[i][j] * phi_i(t),  phi = (g0, g1, sin t, cos t, 1)
// M[h][i][j] = SCL * sum_d qcoef[i][h8+d] * kcoef[j][h8+d]
__global__ __launch_bounds__(512) void coef_kernel(
    const float* __restrict__ attn_in_w, const float* __restrict__ attn_in_b,
    const float* __restrict__ lookup_w, const float* __restrict__ lookup_b,
    const float* __restrict__ posres_w, const float* __restrict__ posres_b,
    float* __restrict__ coef, float* __restrict__ Mh) {
  int j = threadIdx.x;
  __shared__ float cL[5][G3];
  if (j < G3) {
    float u0 = 0.f, u1 = 0.f, cs = 0.f, cc = 0.f, cb = 0.f;
    const float* wrow = attn_in_w + j * EE;
    for (int e = 0; e < EE; ++e) {
      float w = wrow[e];
      float pw0 = posres_w[e * 2], pw1 = posres_w[e * 2 + 1];
      u0 += w * (lookup_w[e * 2] + pw0);
      u1 += w * (lookup_w[e * 2 + 1] + pw1);
      cs += w * pw0;
      cc += w * pw1;
      cb += w * (lookup_b[e] + posres_b[e]);
    }
    cb += attn_in_b[j];
    coef[0 * G3 + j] = u0;
    coef[1 * G3 + j] = u1;
    coef[2 * G3 + j] = cs;
    coef[3 * G3 + j] = cc;
    coef[4 * G3 + j] = cb;
    cL[0][j] = u0;
    cL[1][j] = u1;
    cL[2][j] = cs;
    cL[3][j] = cc;
    cL[4][j] = cb;
  }
  __syncthreads();
  if (j < NHH * 25) {
    int h = j / 25;
    int ij = j % 25;
    int i = ij / 5, jj = ij % 5;
    const float SCL = 0.35355339059327373f * 1.4426950408889634f;
    float acc = 0.f;
#pragma unroll
    for (int d = 0; d < HDD; ++d)
      acc += cL[i][h * HDD + d] * cL[jj][EE + h * HDD + d];
    Mh[h * 25 + ij] = acc * SCL;
  }
}

// K1: GRU. One block per (input s, batch b). 512 threads = 128 groups of 4.
// launch_bounds(512,1): VGPR cap 256 so the 24 float4 weights STAY resident.
__global__ __launch_bounds__(512, 1) void gru_kernel(
    const float* __restrict__ in0, const float* __restrict__ in1,
    const float* __restrict__ in2, const int* __restrict__ len0,
    const int* __restrict__ len1, const int* __restrict__ len2,
    const float* __restrict__ w_ih, const float* __restrict__ w_hh,
    const float* __restrict__ b_ih, const float* __restrict__ b_hh,
    float* __restrict__ coor_embs) {
  int blk = blockIdx.x;
  int s = blk >> 5;
  int b = blk & 31;
  const float* inp = (s == 0) ? in0 : (s == 1) ? in1 : in2;
  const int* lenp = (s == 0) ? len0 : (s == 1) ? len1 : len2;
  int len = lenp[b];
  int tid = threadIdx.x;
  int e = tid >> 2;   // h element / gate index 0..127
  int kp = tid & 3;   // k-slice 0..3

  __shared__ __align__(16) float hb[2][EE];
  __shared__ __align__(16) float xst[TT * 2];

  {
    int t = tid;
    float4 v = *(const float4*)(inp + ((size_t)b * TT + t) * 4);
    xst[t * 2] = v.x;
    xst[t * 2 + 1] = v.y;
  }
  if (tid < EE) hb[0][tid] = 0.0f;

  int rr = e, rz = e + 128, rn = e + 256;
  const float* prr = w_hh + (size_t)rr * EE + 4 * kp;
  const float* prz = w_hh + (size_t)rz * EE + 4 * kp;
  const float* prn = w_hh + (size_t)rn * EE + 4 * kp;
#define LD4(p) (*(const float4*)(p))
  float4 wr0 = LD4(prr + 0),  wr1 = LD4(prr + 16), wr2 = LD4(prr + 32),
         wr3 = LD4(prr + 48), wr4 = LD4(prr + 64), wr5 = LD4(prr + 80),
         wr6 = LD4(prr + 96), wr7 = LD4(prr + 112);
  float4 wz0 = LD4(prz + 0),  wz1 = LD4(prz + 16), wz2 = LD4(prz + 32),
         wz3 = LD4(prz + 48), wz4 = LD4(prz + 64), wz5 = LD4(prz + 80),
         wz6 = LD4(prz + 96), wz7 = LD4(prz + 112);
  float4 wn0 = LD4(prn + 0),  wn1 = LD4(prn + 16), wn2 = LD4(prn + 32),
         wn3 = LD4(prn + 48), wn4 = LD4(prn + 64), wn5 = LD4(prn + 80),
         wn6 = LD4(prn + 96), wn7 = LD4(prn + 112);

  float br = b_ih[rr] + b_hh[rr];
  float bz = b_ih[rz] + b_hh[rz];
  float bn = b_ih[rn];
  float bhn = b_hh[rn];
  float wir0 = w_ih[rr * 2], wir1 = w_ih[rr * 2 + 1];
  float wiz0 = w_ih[rz * 2], wiz1 = w_ih[rz * 2 + 1];
  float win0 = w_ih[rn * 2], win1 = w_ih[rn * 2 + 1];

  float hold = 0.0f;
  __syncthreads();

#pragma unroll 1
  for (int t = 0; t < len; ++t) {
    const float* hrow = hb[t & 1] + 4 * kp;
    float4 h0 = LD4(hrow + 0),  h1 = LD4(hrow + 16), h2 = LD4(hrow + 32),
           h3 = LD4(hrow + 48), h4v = LD4(hrow + 64), h5 = LD4(hrow + 80),
           h6 = LD4(hrow + 96), h7 = LD4(hrow + 112);
    float x0 = xst[t * 2], x1 = xst[t * 2 + 1];

    float hra = DOT4(wr0, h0) + DOT4(wr1, h1) + DOT4(wr2, h2) + DOT4(wr3, h3);
    float hrb = DOT4(wr4, h4v) + DOT4(wr5, h5) + DOT4(wr6, h6) + DOT4(wr7, h7);
    float hza = DOT4(wz0, h0) + DOT4(wz1, h1) + DOT4(wz2, h2) + DOT4(wz3, h3);
    float hzb = DOT4(wz4, h4v) + DOT4(wz5, h5) + DOT4(wz6, h6) + DOT4(wz7, h7);
    float hna = DOT4(wn0, h0) + DOT4(wn1, h1) + DOT4(wn2, h2) + DOT4(wn3, h3);
    float hnb = DOT4(wn4, h4v) + DOT4(wn5, h5) + DOT4(wn6, h6) + DOT4(wn7, h7);
    float hr = hra + hrb, hz = hza + hzb, hn = hna + hnb;

    hr += __shfl_xor(hr, 1);
    hz += __shfl_xor(hz, 1);
    hn += __shfl_xor(hn, 1);
    hr += __shfl_xor(hr, 2);
    hz += __shfl_xor(hz, 2);
    hn += __shfl_xor(hn, 2);

    float r = sigmoidf_(br + wir0 * x0 + wir1 * x1 + hr);
    float z = sigmoidf_(bz + wiz0 * x0 + wiz1 * x1 + hz);
    float targ = bn + win0 * x0 + win1 * x1 + r * (bhn + hn);
    float ex = __expf(2.0f * targ);
    float n = 1.0f - 2.0f * __builtin_amdgcn_rcpf(ex + 1.0f);  // tanh
    hold = n + z * (hold - n);
    if (kp == 0) hb[(t & 1) ^ 1][e] = hold;
    __syncthreads();
  }
  if (kp == 0) coor_embs[(size_t)blk * EE + e] = hold;
}

// K2: attention via rank-5 structure. s_qk = phi(q) . (M phi(k)).
// Stage phi[t] (float4, the varying part) and mk[t] = M phi(t) (float4 + float).
// Phase A: rZ_q.  Phase B: w_k = sum_q exp2(s)/Z_q, then accumulate
// wphi = sum_k w_k phi(k) (5-vec) and apply V-coef C once at the end.
__global__ __launch_bounds__(256) void attn_kernel(const float* __restrict__ in0,
                                                   const float* __restrict__ in1,
                                                   const float* __restrict__ in2,
                                                   const float* __restrict__ coef,
                                                   const float* __restrict__ Mh,
                                                   float* __restrict__ ohat) {
  int blk = blockIdx.x;  // s*512 + b*16 + h
  int s = blk >> 9;
  int bh = blk & 511;
  int b = bh >> 4;
  int h = bh & 15;
  const float* inp = (s == 0) ? in0 : (s == 1) ? in1 : in2;
  int tid = threadIdx.x;

  __shared__ __align__(16) float4 phiL[TT];
  __shared__ __align__(16) float4 mk4L[TT];
  __shared__ float mk1L[TT];
  __shared__ float rZ[TT];
  __shared__ float red[4][8];

  // per-head 5x5 M (uniform -> scalar regs)
  float M[25];
#pragma unroll
  for (int i = 0; i < 25; ++i) M[i] = Mh[h * 25 + i];

  for (int t = tid; t < TT; t += 256) {
    float ft = (float)t;
    float st = sinf(ft);
    float ct = cosf(ft);
    float4 g = *(const float4*)(inp + ((size_t)b * TT + t) * 4);
    float4 phi = make_float4(g.z, g.w, st, ct);
    phiL[t] = phi;
    float m0 = fmaf(M[0], phi.x, fmaf(M[1], phi.y, fmaf(M[2], phi.z, fmaf(M[3], phi.w, M[4]))));
    float m1 = fmaf(M[5], phi.x, fmaf(M[6], phi.y, fmaf(M[7], phi.z, fmaf(M[8], phi.w, M[9]))));
    float m2 = fmaf(M[10], phi.x, fmaf(M[11], phi.y, fmaf(M[12], phi.z, fmaf(M[13], phi.w, M[14]))));
    float m3 = fmaf(M[15], phi.x, fmaf(M[16], phi.y, fmaf(M[17], phi.z, fmaf(M[18], phi.w, M[19]))));
    float m4 = fmaf(M[20], phi.x, fmaf(M[21], phi.y, fmaf(M[22], phi.z, fmaf(M[23], phi.w, M[24]))));
    mk4L[t] = make_float4(m0, m1, m2, m3);
    mk1L[t] = m4;
  }
  __syncthreads();

  // Phase A: per q-row denominators (scores tiny -> max-free softmax is safe)
  {
    float4 p0 = phiL[tid];
    float4 p1 = phiL[tid + 256];
    float Z0a = 0.f, Z0b = 0.f, Z1a = 0.f, Z1b = 0.f;
#pragma unroll 1
    for (int k = 0; k < TT; k += 2) {
      float4 ma = mk4L[k];
      float na = mk1L[k];
      float4 mb = mk4L[k + 1];
      float nb = mk1L[k + 1];
      Z0a += exp2_(SC5(p0, ma, na));
      Z0b += exp2_(SC5(p0, mb, nb));
      Z1a += exp2_(SC5(p1, ma, na));
      Z1b += exp2_(SC5(p1, mb, nb));
    }
    rZ[tid] = 1.0f / ((Z0a + Z0b) * (float)TT);
    rZ[tid + 256] = 1.0f / ((Z1a + Z1b) * (float)TT);
  }
  __syncthreads();

  // Phase B: thread owns k-rows tid, tid+256
  {
    float4 m0 = mk4L[tid];
    float n0 = mk1L[tid];
    float4 m1 = mk4L[tid + 256];
    float n1 = mk1L[tid + 256];
    float w0a = 0.f, w0b = 0.f, w1a = 0.f, w1b = 0.f;
#pragma unroll 1
    for (int q = 0; q < TT; q += 2) {
      float4 pa = phiL[q];
      float4 pb = phiL[q + 1];
      float rza = rZ[q];
      float rzb = rZ[q + 1];
      w0a = fmaf(exp2_(SC5(pa, m0, n0)), rza, w0a);
      w0b = fmaf(exp2_(SC5(pb, m0, n0)), rzb, w0b);
      w1a = fmaf(exp2_(SC5(pa, m1, n1)), rza, w1a);
      w1b = fmaf(exp2_(SC5(pb, m1, n1)), rzb, w1b);
    }
    float w0 = w0a + w0b, w1 = w1a + w1b;
    float4 f0 = phiL[tid];
    float4 f1 = phiL[tid + 256];
    float od[5];
    od[0] = w0 * f0.x + w1 * f1.x;
    od[1] = w0 * f0.y + w1 * f1.y;
    od[2] = w0 * f0.z + w1 * f1.z;
    od[3] = w0 * f0.w + w1 * f1.w;
    od[4] = w0 + w1;
#pragma unroll
    for (int off = 32; off >= 1; off >>= 1) {
#pragma unroll
      for (int d = 0; d < 5; ++d) od[d] += __shfl_xor(od[d], off, 64);
    }
    int wave = tid >> 6;
    int lane = tid & 63;
    if (lane == 0) {
#pragma unroll
      for (int d = 0; d < 5; ++d) red[wave][d] = od[d];
    }
  }
  __syncthreads();
  if (tid < HDD) {
    float wp0 = red[0][0] + red[1][0] + red[2][0] + red[3][0];
    float wp1 = red[0][1] + red[1][1] + red[2][1] + red[3][1];
    float wp2 = red[0][2] + red[1][2] + red[2][2] + red[3][2];
    float wp3 = red[0][3] + red[1][3] + red[2][3] + red[3][3];
    float wp4 = red[0][4] + red[1][4] + red[2][4] + red[3][4];
    int jv = 2 * EE + h * HDD + tid;
    float o = coef[jv] * wp0 + coef[G3 + jv] * wp1 + coef[2 * G3 + jv] * wp2 +
              coef[3 * G3 + jv] * wp3 + coef[4 * G3 + jv] * wp4;
    ohat[(size_t)blk * HDD + tid] = o;
  }
}

// K3: grid_emb = ohat @ out_w.T + out_b ; out = gamma*coor + (1-gamma)*grid
__global__ __launch_bounds__(128) void finalize_kernel(
    const float* __restrict__ attn_out_w, const float* __restrict__ attn_out_b,
    const float* __restrict__ ohat, const float* __restrict__ coor_embs,
    const float* __restrict__ gamma_p, float* __restrict__ out) {
  int blk = blockIdx.x;  // s*32 + b
  int e = threadIdx.x;
  __shared__ float ov[EE];
  ov[e] = ohat[(size_t)blk * EE + e];
  __syncthreads();
  float acc = attn_out_b[e];
  const float* wrow = attn_out_w + (size_t)e * EE;
#pragma unroll 8
  for (int f = 0; f < EE; ++f) acc += wrow[f] * ov[f];
  float g = gamma_p[0];
  out[(size_t)blk * EE + e] = g * coor_embs[(size_t)blk * EE + e] + (1.0f - g) * acc;
}

// K4: pos/neg distances from the embeddings already in d_out
__global__ void dist_kernel(float* __restrict__ out) {
  int i = threadIdx.x;  // 64 threads
  int b = i & 31;
  int neg = i >> 5;
  const float* a = out + (size_t)b * EE;
  const float* x = out + (size_t)(1 + neg) * BB * EE + (size_t)b * EE;
  float sum = 0.f;
  for (int e = 0; e < EE; ++e) {
    float d = a[e] - x[e] + 1e-6f;
    sum += d * d;
  }
  out[3 * BB * EE + neg * BB + b] = expf(-sqrtf(sum));
}

extern "C" void kernel_launch(void* const* d_in, const int* in_sizes, int n_in,
                              void* d_out, int out_size, void* d_ws, size_t ws_size,
                              hipStream_t stream) {
  const float* a_in = (const float*)d_in[0];
  const float* p_in = (const float*)d_in[1];
  const float* ng_in = (const float*)d_in[2];
  const int* a_len = (const int*)d_in[3];
  const int* p_len = (const int*)d_in[4];
  const int* ng_len = (const int*)d_in[5];
  const float* w_ih = (const float*)d_in[6];
  const float* w_hh = (const float*)d_in[7];
  const float* b_ih = (const float*)d_in[8];
  const float* b_hh = (const float*)d_in[9];
  const float* lookup_w = (const float*)d_in[10];
  const float* lookup_b = (const float*)d_in[11];
  const float* posres_w = (const float*)d_in[12];
  const float* posres_b = (const float*)d_in[13];
  const float* attn_in_w = (const float*)d_in[14];
  const float* attn_in_b = (const float*)d_in[15];
  const float* attn_out_w = (const float*)d_in[16];
  const float* attn_out_b = (const float*)d_in[17];
  const float* gamma_p = (const float*)d_in[18];
  float* out = (float*)d_out;

  float* coef = (float*)d_ws;      // 5*384 = 1920 floats (pad to 2048)
  float* Mh = coef + 2048;         // 16*25 = 400 floats (pad to 512)
  float* ohat = Mh + 512;          // 3*32*16*8 = 12288 floats
  float* cemb = ohat + 12288;      // 3*32*128  = 12288 floats

  hipLaunchKernelGGL(coef_kernel, dim3(1), dim3(512), 0, stream, attn_in_w,
                     attn_in_b, lookup_w, lookup_b, posres_w, posres_b, coef, Mh);
  hipLaunchKernelGGL(attn_kernel, dim3(1536), dim3(256), 0, stream, a_in, p_in,
                     ng_in, coef, Mh, ohat);
  hipLaunchKernelGGL(gru_kernel, dim3(96), dim3(512), 0, stream, a_in, p_in, ng_in,
                     a_len, p_len, ng_len, w_ih, w_hh, b_ih, b_hh, cemb);
  hipLaunchKernelGGL(finalize_kernel, dim3(96), dim3(128), 0, stream, attn_out_w,
                     attn_out_b, ohat, cemb, gamma_p, out);
  hipLaunchKernelGGL(dist_kernel, dim3(1), dim3(64), 0, stream, out);
}

// Round 7
// 457.059 us; speedup vs baseline: 1.7826x; 1.1031x over previous
//
#include <hip/hip_runtime.h>
#include <math.h>

#define BB 32
#define TT 512
#define EE 128
#define NHH 16
#define HDD 8
#define G3 384

__device__ __forceinline__ float sigmoidf_(float x) {
  return __builtin_amdgcn_rcpf(1.0f + __expf(-x));
}

__device__ __forceinline__ float exp2_(float x) {
#if __has_builtin(__builtin_amdgcn_exp2f)
  return __builtin_amdgcn_exp2f(x);
#else
  return exp2f(x);
#endif
}

#define DOT4(p, q) fmaf((p).x, (q).x, fmaf((p).y, (q).y, fmaf((p).z, (q).z, (p).w * (q).w)))
// 5-term: dot(p,m) + n as a single fma chain
#define SC5(p, m, n) \
  fmaf((p).x, (m).x, fmaf((p).y, (m).y, fmaf((p).z, (m).z, fmaf((p).w, (m).w, (n)))))
// opaque def: forbids rematerialization of a loaded value (keeps it in a VGPR)
#define PIN4(v) asm volatile("" : "+v"((v).x), "+v"((v).y), "+v"((v).z), "+v"((v).w))

// K0: fold lookup/posres/attn_in into coef[5][384] and per-head 5x5 M (scaled).
__global__ __launch_bounds__(512) void coef_kernel(
    const float* __restrict__ attn_in_w, const float* __restrict__ attn_in_b,
    const float* __restrict__ lookup_w, const float* __restrict__ lookup_b,
    const float* __restrict__ posres_w, const float* __restrict__ posres_b,
    float* __restrict__ coef, float* __restrict__ Mh) {
  int j = threadIdx.x;
  __shared__ float cL[5][G3];
  if (j < G3) {
    float u0 = 0.f, u1 = 0.f, cs = 0.f, cc = 0.f, cb = 0.f;
    const float* wrow = attn_in_w + j * EE;
    for (int e = 0; e < EE; ++e) {
      float w = wrow[e];
      float pw0 = posres_w[e * 2], pw1 = posres_w[e * 2 + 1];
      u0 += w * (lookup_w[e * 2] + pw0);
      u1 += w * (lookup_w[e * 2 + 1] + pw1);
      cs += w * pw0;
      cc += w * pw1;
      cb += w * (lookup_b[e] + posres_b[e]);
    }
    cb += attn_in_b[j];
    coef[0 * G3 + j] = u0;
    coef[1 * G3 + j] = u1;
    coef[2 * G3 + j] = cs;
    coef[3 * G3 + j] = cc;
    coef[4 * G3 + j] = cb;
    cL[0][j] = u0;
    cL[1][j] = u1;
    cL[2][j] = cs;
    cL[3][j] = cc;
    cL[4][j] = cb;
  }
  __syncthreads();
  if (j < NHH * 25) {
    int h = j / 25;
    int ij = j % 25;
    int i = ij / 5, jj = ij % 5;
    const float SCL = 0.35355339059327373f * 1.4426950408889634f;
    float acc = 0.f;
#pragma unroll
    for (int d = 0; d < HDD; ++d)
      acc += cL[i][h * HDD + d] * cL[jj][EE + h * HDD + d];
    Mh[h * 25 + ij] = acc * SCL;
  }
}

// K1: GRU. One block per (input s, batch b). 512 threads = 128 groups of 4.
// Weights loaded once and PINNED via opaque asm defs (no remat -> no L2 re-reads).
__global__ __launch_bounds__(512, 1) void gru_kernel(
    const float* __restrict__ in0, const float* __restrict__ in1,
    const float* __restrict__ in2, const int* __restrict__ len0,
    const int* __restrict__ len1, const int* __restrict__ len2,
    const float* __restrict__ w_ih, const float* __restrict__ w_hh,
    const float* __restrict__ b_ih, const float* __restrict__ b_hh,
    float* __restrict__ coor_embs) {
  int blk = blockIdx.x;
  int s = blk >> 5;
  int b = blk & 31;
  const float* inp = (s == 0) ? in0 : (s == 1) ? in1 : in2;
  const int* lenp = (s == 0) ? len0 : (s == 1) ? len1 : len2;
  int len = lenp[b];
  int tid = threadIdx.x;
  int e = tid >> 2;   // h element / gate index 0..127
  int kp = tid & 3;   // k-slice 0..3

  __shared__ __align__(16) float hb[2][EE];
  __shared__ __align__(16) float xst[TT * 2];

  {
    int t = tid;
    float4 v = *(const float4*)(inp + ((size_t)b * TT + t) * 4);
    xst[t * 2] = v.x;
    xst[t * 2 + 1] = v.y;
  }
  if (tid < EE) hb[0][tid] = 0.0f;

  int rr = e, rz = e + 128, rn = e + 256;
  const float* prr = w_hh + (size_t)rr * EE + 4 * kp;
  const float* prz = w_hh + (size_t)rz * EE + 4 * kp;
  const float* prn = w_hh + (size_t)rn * EE + 4 * kp;
#define LD4(p) (*(const float4*)(p))
  float4 wr0 = LD4(prr + 0),  wr1 = LD4(prr + 16), wr2 = LD4(prr + 32),
         wr3 = LD4(prr + 48), wr4 = LD4(prr + 64), wr5 = LD4(prr + 80),
         wr6 = LD4(prr + 96), wr7 = LD4(prr + 112);
  float4 wz0 = LD4(prz + 0),  wz1 = LD4(prz + 16), wz2 = LD4(prz + 32),
         wz3 = LD4(prz + 48), wz4 = LD4(prz + 64), wz5 = LD4(prz + 80),
         wz6 = LD4(prz + 96), wz7 = LD4(prz + 112);
  float4 wn0 = LD4(prn + 0),  wn1 = LD4(prn + 16), wn2 = LD4(prn + 32),
         wn3 = LD4(prn + 48), wn4 = LD4(prn + 64), wn5 = LD4(prn + 80),
         wn6 = LD4(prn + 96), wn7 = LD4(prn + 112);
  PIN4(wr0); PIN4(wr1); PIN4(wr2); PIN4(wr3);
  PIN4(wr4); PIN4(wr5); PIN4(wr6); PIN4(wr7);
  PIN4(wz0); PIN4(wz1); PIN4(wz2); PIN4(wz3);
  PIN4(wz4); PIN4(wz5); PIN4(wz6); PIN4(wz7);
  PIN4(wn0); PIN4(wn1); PIN4(wn2); PIN4(wn3);
  PIN4(wn4); PIN4(wn5); PIN4(wn6); PIN4(wn7);

  float br = b_ih[rr] + b_hh[rr];
  float bz = b_ih[rz] + b_hh[rz];
  float bn = b_ih[rn];
  float bhn = b_hh[rn];
  float wir0 = w_ih[rr * 2], wir1 = w_ih[rr * 2 + 1];
  float wiz0 = w_ih[rz * 2], wiz1 = w_ih[rz * 2 + 1];
  float win0 = w_ih[rn * 2], win1 = w_ih[rn * 2 + 1];

  float hold = 0.0f;
  __syncthreads();

#pragma unroll 1
  for (int t = 0; t < len; ++t) {
    const float* hrow = hb[t & 1] + 4 * kp;
    float4 h0 = LD4(hrow + 0),  h1 = LD4(hrow + 16), h2 = LD4(hrow + 32),
           h3 = LD4(hrow + 48), h4v = LD4(hrow + 64), h5 = LD4(hrow + 80),
           h6 = LD4(hrow + 96), h7 = LD4(hrow + 112);
    float x0 = xst[t * 2], x1 = xst[t * 2 + 1];

    float hra = DOT4(wr0, h0) + DOT4(wr1, h1) + DOT4(wr2, h2) + DOT4(wr3, h3);
    float hrb = DOT4(wr4, h4v) + DOT4(wr5, h5) + DOT4(wr6, h6) + DOT4(wr7, h7);
    float hza = DOT4(wz0, h0) + DOT4(wz1, h1) + DOT4(wz2, h2) + DOT4(wz3, h3);
    float hzb = DOT4(wz4, h4v) + DOT4(wz5, h5) + DOT4(wz6, h6) + DOT4(wz7, h7);
    float hna = DOT4(wn0, h0) + DOT4(wn1, h1) + DOT4(wn2, h2) + DOT4(wn3, h3);
    float hnb = DOT4(wn4, h4v) + DOT4(wn5, h5) + DOT4(wn6, h6) + DOT4(wn7, h7);
    float hr = hra + hrb, hz = hza + hzb, hn = hna + hnb;

    hr += __shfl_xor(hr, 1);
    hz += __shfl_xor(hz, 1);
    hn += __shfl_xor(hn, 1);
    hr += __shfl_xor(hr, 2);
    hz += __shfl_xor(hz, 2);
    hn += __shfl_xor(hn, 2);

    float r = sigmoidf_(br + wir0 * x0 + wir1 * x1 + hr);
    float z = sigmoidf_(bz + wiz0 * x0 + wiz1 * x1 + hz);
    float targ = bn + win0 * x0 + win1 * x1 + r * (bhn + hn);
    float ex = __expf(2.0f * targ);
    float n = 1.0f - 2.0f * __builtin_amdgcn_rcpf(ex + 1.0f);  // tanh
    hold = n + z * (hold - n);
    if (kp == 0) hb[(t & 1) ^ 1][e] = hold;
    __syncthreads();
  }
  if (kp == 0) coor_embs[(size_t)blk * EE + e] = hold;
}

// K2: attention via rank-5 structure, SINGLE pass.
// s_qk = phi(q).(M phi(k));  N_q = sum_k exp2(s) phi(k) (4-vec), Z_q = sum_k exp2(s)
// o = C . ( (1/T) sum_q N_q/Z_q , 1 )
__global__ __launch_bounds__(256) void attn_kernel(const float* __restrict__ in0,
                                                   const float* __restrict__ in1,
                                                   const float* __restrict__ in2,
                                                   const float* __restrict__ coef,
                                                   const float* __restrict__ Mh,
                                                   float* __restrict__ ohat) {
  int blk = blockIdx.x;  // s*512 + b*16 + h
  int s = blk >> 9;
  int bh = blk & 511;
  int b = bh >> 4;
  int h = bh & 15;
  const float* inp = (s == 0) ? in0 : (s == 1) ? in1 : in2;
  int tid = threadIdx.x;

  __shared__ __align__(16) float4 phiL[TT];
  __shared__ __align__(16) float4 mk4L[TT];
  __shared__ float mk1L[TT];
  __shared__ float red[4][4];

  float M[25];
#pragma unroll
  for (int i = 0; i < 25; ++i) M[i] = Mh[h * 25 + i];

  for (int t = tid; t < TT; t += 256) {
    float ft = (float)t;
    float st = sinf(ft);
    float ct = cosf(ft);
    float4 g = *(const float4*)(inp + ((size_t)b * TT + t) * 4);
    float4 phi = make_float4(g.z, g.w, st, ct);
    phiL[t] = phi;
    float m0 = fmaf(M[0], phi.x, fmaf(M[1], phi.y, fmaf(M[2], phi.z, fmaf(M[3], phi.w, M[4]))));
    float m1 = fmaf(M[5], phi.x, fmaf(M[6], phi.y, fmaf(M[7], phi.z, fmaf(M[8], phi.w, M[9]))));
    float m2 = fmaf(M[10], phi.x, fmaf(M[11], phi.y, fmaf(M[12], phi.z, fmaf(M[13], phi.w, M[14]))));
    float m3 = fmaf(M[15], phi.x, fmaf(M[16], phi.y, fmaf(M[17], phi.z, fmaf(M[18], phi.w, M[19]))));
    float m4 = fmaf(M[20], phi.x, fmaf(M[21], phi.y, fmaf(M[22], phi.z, fmaf(M[23], phi.w, M[24]))));
    mk4L[t] = make_float4(m0, m1, m2, m3);
    mk1L[t] = m4;
  }
  __syncthreads();

  // One pass: thread owns q-rows tid and tid+256.
  float od0, od1, od2, od3;
  {
    float4 p0 = phiL[tid];
    float4 p1 = phiL[tid + 256];
    float Z0 = 0.f, Z1 = 0.f;
    float n00 = 0.f, n01 = 0.f, n02 = 0.f, n03 = 0.f;
    float n10 = 0.f, n11 = 0.f, n12 = 0.f, n13 = 0.f;
#pragma unroll 2
    for (int k = 0; k < TT; ++k) {
      float4 m = mk4L[k];
      float n = mk1L[k];
      float4 f = phiL[k];
      float e0 = exp2_(SC5(p0, m, n));
      float e1 = exp2_(SC5(p1, m, n));
      Z0 += e0;
      Z1 += e1;
      n00 = fmaf(e0, f.x, n00);
      n01 = fmaf(e0, f.y, n01);
      n02 = fmaf(e0, f.z, n02);
      n03 = fmaf(e0, f.w, n03);
      n10 = fmaf(e1, f.x, n10);
      n11 = fmaf(e1, f.y, n11);
      n12 = fmaf(e1, f.z, n12);
      n13 = fmaf(e1, f.w, n13);
    }
    float rz0 = 1.0f / (Z0 * (float)TT);
    float rz1 = 1.0f / (Z1 * (float)TT);
    od0 = n00 * rz0 + n10 * rz1;
    od1 = n01 * rz0 + n11 * rz1;
    od2 = n02 * rz0 + n12 * rz1;
    od3 = n03 * rz0 + n13 * rz1;
  }
#pragma unroll
  for (int off = 32; off >= 1; off >>= 1) {
    od0 += __shfl_xor(od0, off, 64);
    od1 += __shfl_xor(od1, off, 64);
    od2 += __shfl_xor(od2, off, 64);
    od3 += __shfl_xor(od3, off, 64);
  }
  {
    int wave = tid >> 6;
    int lane = tid & 63;
    if (lane == 0) {
      red[wave][0] = od0;
      red[wave][1] = od1;
      red[wave][2] = od2;
      red[wave][3] = od3;
    }
  }
  __syncthreads();
  if (tid < HDD) {
    float wp0 = red[0][0] + red[1][0] + red[2][0] + red[3][0];
    float wp1 = red[0][1] + red[1][1] + red[2][1] + red[3][1];
    float wp2 = red[0][2] + red[1][2] + red[2][2] + red[3][2];
    float wp3 = red[0][3] + red[1][3] + red[2][3] + red[3][3];
    int jv = 2 * EE + h * HDD + tid;
    float o = coef[jv] * wp0 + coef[G3 + jv] * wp1 + coef[2 * G3 + jv] * wp2 +
              coef[3 * G3 + jv] * wp3 + coef[4 * G3 + jv];  // wp4 == 1 exactly
    ohat[(size_t)blk * HDD + tid] = o;
  }
}

// K3: grid_emb = ohat @ out_w.T + out_b ; out = gamma*coor + (1-gamma)*grid
__global__ __launch_bounds__(128) void finalize_kernel(
    const float* __restrict__ attn_out_w, const float* __restrict__ attn_out_b,
    const float* __restrict__ ohat, const float* __restrict__ coor_embs,
    const float* __restrict__ gamma_p, float* __restrict__ out) {
  int blk = blockIdx.x;  // s*32 + b
  int e = threadIdx.x;
  __shared__ float ov[EE];
  ov[e] = ohat[(size_t)blk * EE + e];
  __syncthreads();
  float acc = attn_out_b[e];
  const float* wrow = attn_out_w + (size_t)e * EE;
#pragma unroll 8
  for (int f = 0; f < EE; ++f) acc += wrow[f] * ov[f];
  float g = gamma_p[0];
  out[(size_t)blk * EE + e] = g * coor_embs[(size_t)blk * EE + e] + (1.0f - g) * acc;
}

// K4: pos/neg distances from the embeddings already in d_out
__global__ void dist_kernel(float* __restrict__ out) {
  int i = threadIdx.x;  // 64 threads
  int b = i & 31;
  int neg = i >> 5;
  const float* a = out + (size_t)b * EE;
  const float* x = out + (size_t)(1 + neg) * BB * EE + (size_t)b * EE;
  float sum = 0.f;
  for (int e = 0; e < EE; ++e) {
    float d = a[e] - x[e] + 1e-6f;
    sum += d * d;
  }
  out[3 * BB * EE + neg * BB + b] = expf(-sqrtf(sum));
}

extern "C" void kernel_launch(void* const* d_in, const int* in_sizes, int n_in,
                              void* d_out, int out_size, void* d_ws, size_t ws_size,
                              hipStream_t stream) {
  const float* a_in = (const float*)d_in[0];
  const float* p_in = (const float*)d_in[1];
  const float* ng_in = (const float*)d_in[2];
  const int* a_len = (const int*)d_in[3];
  const int* p_len = (const int*)d_in[4];
  const int* ng_len = (const int*)d_in[5];
  const float* w_ih = (const float*)d_in[6];
  const float* w_hh = (const float*)d_in[7];
  const float* b_ih = (const float*)d_in[8];
  const float* b_hh = (const float*)d_in[9];
  const float* lookup_w = (const float*)d_in[10];
  const float* lookup_b = (const float*)d_in[11];
  const float* posres_w = (const float*)d_in[12];
  const float* posres_b = (const float*)d_in[13];
  const float* attn_in_w = (const float*)d_in[14];
  const float* attn_in_b = (const float*)d_in[15];
  const float* attn_out_w = (const float*)d_in[16];
  const float* attn_out_b = (const float*)d_in[17];
  const float* gamma_p = (const float*)d_in[18];
  float* out = (float*)d_out;

  float* coef = (float*)d_ws;      // 5*384 = 1920 floats (pad to 2048)
  float* Mh = coef + 2048;         // 16*25 = 400 floats (pad to 512)
  float* ohat = Mh + 512;          // 3*32*16*8 = 12288 floats
  float* cemb = ohat + 12288;      // 3*32*128  = 12288 floats

  hipLaunchKernelGGL(coef_kernel, dim3(1), dim3(512), 0, stream, attn_in_w,
                     attn_in_b, lookup_w, lookup_b, posres_w, posres_b, coef, Mh);
  hipLaunchKernelGGL(attn_kernel, dim3(1536), dim3(256), 0, stream, a_in, p_in,
                     ng_in, coef, Mh, ohat);
  hipLaunchKernelGGL(gru_kernel, dim3(96), dim3(512), 0, stream, a_in, p_in, ng_in,
                     a_len, p_len, ng_len, w_ih, w_hh, b_ih, b_hh, cemb);
  hipLaunchKernelGGL(finalize_kernel, dim3(96), dim3(128), 0, stream, attn_out_w,
                     attn_out_b, ohat, cemb, gamma_p, out);
  hipLaunchKernelGGL(dist_kernel, dim3(1), dim3(64), 0, stream, out);
}